// Round 1
// baseline (1303.455 us; speedup 1.0000x reference)
//
#include <hip/hip_runtime.h>

// Problem constants: Q,K,V (4,8,1024,64) f32.
#define BATCH 4
#define HEADS 8
#define SEQ   1024
#define DIM   64
#define NCOL  512            // HEADS*DIM, columns of the flat (1024,512) view
#define SCALE 0.125f

// ws layout (float offsets)
//  FQ:   0          (4*1024*512 = 2097152)
//  FK:   2097152
//  CN:   4194304    (512*512   = 262144)
//  SN:   4456448
//  CM:   4718592    (1024*1024 = 1048576)
//  SM:   5767168
//  T:    6815744    (4 arrays * 2097152 = 8388608)   [dead after stage2]
//  Qp:   6815744    (8388608)  -- overwrites T region
//  Kp:   15204352   (8388608)
//  end:  23592960 floats = 94,371,840 bytes
#define WS_FLOATS_NEEDED 23592960ull

// ---------------------------------------------------------------- trig tables
__global__ void gen_mats(float* __restrict__ CN, float* __restrict__ SN,
                         float* __restrict__ CM, float* __restrict__ SM) {
    int idx = blockIdx.x * 256 + threadIdx.x;
    const float twopi = 6.28318530717958647692f;
    if (idx < 512 * 512) {
        int a = idx >> 9, b = idx & 511;
        int t = (a * b) & 511;
        float s, c;
        sincosf(twopi * (float)t * (1.0f / 512.0f), &s, &c);
        CN[idx] = c; SN[idx] = s;
    }
    int idx2 = idx - 512 * 512;
    if (idx2 >= 0 && idx2 < 1024 * 1024) {
        int a = idx2 >> 10, b = idx2 & 1023;
        int t = (a * b) & 1023;
        float s, c;
        sincosf(twopi * (float)t * (1.0f / 1024.0f), &s, &c);
        CM[idx2] = c; SM[idx2] = s;
    }
}

// ------------------------------------------------- generic f32 GEMM  C = A*B
// A (M,K), B (K,N), C (M,N), all row-major, M%64==0, N%64==0, K%16==0.
__global__ __launch_bounds__(256) void gemm_nn(const float* __restrict__ A,
                                               const float* __restrict__ B,
                                               float* __restrict__ C,
                                               int M, int N, int K) {
    __shared__ float As[64][17];
    __shared__ float Bs[16][64];
    int tx = threadIdx.x & 15, ty = threadIdx.x >> 4;
    int m0 = blockIdx.y * 64, n0 = blockIdx.x * 64;
    float acc[4][4] = {};
    for (int k0 = 0; k0 < K; k0 += 16) {
        {
            int col = threadIdx.x & 15, row = threadIdx.x >> 4;
#pragma unroll
            for (int r = 0; r < 4; r++)
                As[row + 16 * r][col] = A[(size_t)(m0 + row + 16 * r) * K + k0 + col];
            int colb = threadIdx.x & 63, rowb = threadIdx.x >> 6;
#pragma unroll
            for (int r = 0; r < 4; r++)
                Bs[rowb + 4 * r][colb] = B[(size_t)(k0 + rowb + 4 * r) * N + n0 + colb];
        }
        __syncthreads();
#pragma unroll
        for (int kk = 0; kk < 16; kk++) {
            float a[4], b[4];
#pragma unroll
            for (int i = 0; i < 4; i++) a[i] = As[ty + 16 * i][kk];
#pragma unroll
            for (int j = 0; j < 4; j++) b[j] = Bs[kk][tx + 16 * j];
#pragma unroll
            for (int i = 0; i < 4; i++)
#pragma unroll
                for (int j = 0; j < 4; j++) acc[i][j] += a[i] * b[j];
        }
        __syncthreads();
    }
#pragma unroll
    for (int i = 0; i < 4; i++)
#pragma unroll
        for (int j = 0; j < 4; j++)
            C[(size_t)(m0 + ty + 16 * i) * N + n0 + tx + 16 * j] = acc[i][j];
}

// --------------------------------- stage2:  F = CM*Tc - SM*Ts   (batched z=8)
__global__ __launch_bounds__(256) void dft_stage2(const float* __restrict__ CM,
                                                  const float* __restrict__ SM,
                                                  const float* __restrict__ TcQ,
                                                  const float* __restrict__ TsQ,
                                                  const float* __restrict__ TcK,
                                                  const float* __restrict__ TsK,
                                                  float* __restrict__ FQ,
                                                  float* __restrict__ FK) {
    int z = blockIdx.z;                 // 0..7 : input (z>>2), batch (z&3)
    int inp = z >> 2, b = z & 3;
    const float* Tc = (inp ? TcK : TcQ) + (size_t)b * SEQ * NCOL;
    const float* Ts = (inp ? TsK : TsQ) + (size_t)b * SEQ * NCOL;
    float* F = (inp ? FK : FQ) + (size_t)b * SEQ * NCOL;

    __shared__ float Ac[64][17], Asn[64][17];
    __shared__ float Bc[16][64], Bsn[16][64];
    int tx = threadIdx.x & 15, ty = threadIdx.x >> 4;
    int m0 = blockIdx.y * 64, n0 = blockIdx.x * 64;
    float acc[4][4] = {};
    for (int k0 = 0; k0 < 1024; k0 += 16) {
        {
            int col = threadIdx.x & 15, row = threadIdx.x >> 4;
#pragma unroll
            for (int r = 0; r < 4; r++) {
                Ac [row + 16 * r][col] = CM[(size_t)(m0 + row + 16 * r) * 1024 + k0 + col];
                Asn[row + 16 * r][col] = SM[(size_t)(m0 + row + 16 * r) * 1024 + k0 + col];
            }
            int colb = threadIdx.x & 63, rowb = threadIdx.x >> 6;
#pragma unroll
            for (int r = 0; r < 4; r++) {
                Bc [rowb + 4 * r][colb] = Tc[(size_t)(k0 + rowb + 4 * r) * NCOL + n0 + colb];
                Bsn[rowb + 4 * r][colb] = Ts[(size_t)(k0 + rowb + 4 * r) * NCOL + n0 + colb];
            }
        }
        __syncthreads();
#pragma unroll
        for (int kk = 0; kk < 16; kk++) {
            float ac[4], as_[4], bc[4], bs_[4];
#pragma unroll
            for (int i = 0; i < 4; i++) { ac[i] = Ac[ty + 16 * i][kk]; as_[i] = Asn[ty + 16 * i][kk]; }
#pragma unroll
            for (int j = 0; j < 4; j++) { bc[j] = Bc[kk][tx + 16 * j]; bs_[j] = Bsn[kk][tx + 16 * j]; }
#pragma unroll
            for (int i = 0; i < 4; i++)
#pragma unroll
                for (int j = 0; j < 4; j++)
                    acc[i][j] += ac[i] * bc[j] - as_[i] * bs_[j];
        }
        __syncthreads();
    }
#pragma unroll
    for (int i = 0; i < 4; i++)
#pragma unroll
        for (int j = 0; j < 4; j++)
            F[(size_t)(m0 + ty + 16 * i) * NCOL + n0 + tx + 16 * j] = acc[i][j];
}

// ------------------------------------ multi-scale conv gather (per cutoff C)
// out[(b,h,p,l,d)] = bias + sum_ci w[ci] * F[b][(g>>3)+r-C][(g&7)*64+q-C]
// with g=h*1024+l, u=ci*64+d, q=u/C, r=u%C; zero outside [0,1024)x[0,512).
template <int C>
__global__ void gen_conv(const float* __restrict__ F, float* __restrict__ out,
                         const float* __restrict__ w, const float* __restrict__ bias,
                         int p) {
    int idx = blockIdx.x * 256 + threadIdx.x;   // over BATCH*HEADS*SEQ*DIM
    if (idx >= BATCH * HEADS * SEQ * DIM) return;
    int d = idx & 63;
    int l = (idx >> 6) & 1023;
    int h = (idx >> 16) & 7;
    int b = idx >> 19;
    int g  = (h << 10) + l;
    int rb = g >> 3;
    int cb = (g & 7) << 6;
    const float* Fb = F + (size_t)b * (SEQ * NCOL);
    float acc = 0.f;
#pragma unroll
    for (int ci = 0; ci < C; ci++) {
        int u = ci * 64 + d;
        int q = u / C, r = u - q * C;
        int row = rb + r - C;
        int col = cb + q - C;
        if (row >= 0 && col >= 0)
            acc += w[ci] * Fb[(row << 9) + col];
    }
    out[(size_t)((b * 8 + h) * 4 + p) * 65536 + l * 64 + d] = acc + bias[0];
}

// ------------- fused scores (4 GEMMs K=64) + softmax over p + q-reduction
__global__ __launch_bounds__(256) void scores_attn(const float* __restrict__ Qp,
                                                   const float* __restrict__ Kp,
                                                   float* __restrict__ attn_out) {
    int bh = blockIdx.z;
    int k0 = blockIdx.x * 64, q0 = blockIdx.y * 64;
    __shared__ float As[64][68];
    __shared__ float Bs[64][68];
    int tx = threadIdx.x & 15, ty = threadIdx.x >> 4;
    float acc[4][4][4];   // [p][i(q)][j(k)]
#pragma unroll
    for (int p = 0; p < 4; p++)
#pragma unroll
        for (int i = 0; i < 4; i++)
#pragma unroll
            for (int j = 0; j < 4; j++) acc[p][i][j] = 0.f;

    for (int p = 0; p < 4; p++) {
        const float* Ab = Qp + (size_t)(bh * 4 + p) * 65536 + (size_t)q0 * 64;
        const float* Bb = Kp + (size_t)(bh * 4 + p) * 65536 + (size_t)k0 * 64;
        __syncthreads();   // previous iteration's reads complete before overwrite
        {
            int c4 = (threadIdx.x & 15) * 4, row = threadIdx.x >> 4;
#pragma unroll
            for (int r = 0; r < 4; r++) {
                float4 va = *(const float4*)(Ab + (size_t)(row + 16 * r) * 64 + c4);
                As[row + 16 * r][c4 + 0] = va.x; As[row + 16 * r][c4 + 1] = va.y;
                As[row + 16 * r][c4 + 2] = va.z; As[row + 16 * r][c4 + 3] = va.w;
                float4 vb = *(const float4*)(Bb + (size_t)(row + 16 * r) * 64 + c4);
                Bs[row + 16 * r][c4 + 0] = vb.x; Bs[row + 16 * r][c4 + 1] = vb.y;
                Bs[row + 16 * r][c4 + 2] = vb.z; Bs[row + 16 * r][c4 + 3] = vb.w;
            }
        }
        __syncthreads();
#pragma unroll 16
        for (int kk = 0; kk < 64; kk++) {
            float a[4], bv[4];
#pragma unroll
            for (int i = 0; i < 4; i++) a[i] = As[ty + 16 * i][kk];
#pragma unroll
            for (int j = 0; j < 4; j++) bv[j] = Bs[tx + 16 * j][kk];
#pragma unroll
            for (int i = 0; i < 4; i++)
#pragma unroll
                for (int j = 0; j < 4; j++) acc[p][i][j] += a[i] * bv[j];
        }
    }
    __syncthreads();

    // softmax over p per (q,k); accumulate over this thread's 4 q's
    float qsum[4][4];     // [p][j]
#pragma unroll
    for (int p = 0; p < 4; p++)
#pragma unroll
        for (int j = 0; j < 4; j++) qsum[p][j] = 0.f;
#pragma unroll
    for (int i = 0; i < 4; i++)
#pragma unroll
        for (int j = 0; j < 4; j++) {
            float s0 = acc[0][i][j] * SCALE, s1 = acc[1][i][j] * SCALE;
            float s2 = acc[2][i][j] * SCALE, s3 = acc[3][i][j] * SCALE;
            float m = fmaxf(fmaxf(s0, s1), fmaxf(s2, s3));
            float e0 = expf(s0 - m), e1 = expf(s1 - m);
            float e2 = expf(s2 - m), e3 = expf(s3 - m);
            float inv = 1.0f / (e0 + e1 + e2 + e3);
            qsum[0][j] += e0 * inv; qsum[1][j] += e1 * inv;
            qsum[2][j] += e2 * inv; qsum[3][j] += e3 * inv;
        }

    // block-level reduction over the 16 ty groups, then one atomic per (p,k)
    float* red = &As[0][0];   // 4*64*16 = 4096 floats, fits in As
#pragma unroll
    for (int p = 0; p < 4; p++)
#pragma unroll
        for (int j = 0; j < 4; j++)
            red[(p * 64 + tx + 16 * j) * 16 + ty] = qsum[p][j];
    __syncthreads();
    int p = threadIdx.x >> 6, k = threadIdx.x & 63;
    float s = 0.f;
#pragma unroll
    for (int t = 0; t < 16; t++) s += red[(p * 64 + k) * 16 + t];
    atomicAdd(&attn_out[(size_t)(bh * 4 + p) * 1024 + k0 + k], s);
}

// ------------------------------- context[b,h,q,:] = colsum(V[b,h]) broadcast
__global__ __launch_bounds__(256) void context_kernel(const float* __restrict__ V,
                                                      float* __restrict__ out) {
    int bh = blockIdx.x;
    const float* Vb = V + (size_t)bh * 65536;
    __shared__ float part[4][64];
    __shared__ float colsum[64];
    int d = threadIdx.x & 63, grp = threadIdx.x >> 6;
    float s = 0.f;
    for (int r = grp; r < 1024; r += 4) s += Vb[r * 64 + d];
    part[grp][d] = s;
    __syncthreads();
    if (threadIdx.x < 64) colsum[d] = part[0][d] + part[1][d] + part[2][d] + part[3][d];
    __syncthreads();
    float val = colsum[d];
    float* ob = out + (size_t)bh * 65536;
    for (int q = grp; q < 1024; q += 4) ob[q * 64 + d] = val;
}

// ---------------------------------------------------------------------------
extern "C" void kernel_launch(void* const* d_in, const int* in_sizes, int n_in,
                              void* d_out, int out_size, void* d_ws, size_t ws_size,
                              hipStream_t stream) {
    if (n_in < 19) return;
    if ((size_t)ws_size < WS_FLOATS_NEEDED * sizeof(float)) return;  // visible failure
    const float* Q = (const float*)d_in[0];
    const float* K = (const float*)d_in[1];
    const float* V = (const float*)d_in[2];
    const float* wq[4] = {(const float*)d_in[3], (const float*)d_in[5],
                          (const float*)d_in[7], (const float*)d_in[9]};
    const float* bq[4] = {(const float*)d_in[4], (const float*)d_in[6],
                          (const float*)d_in[8], (const float*)d_in[10]};
    const float* wk[4] = {(const float*)d_in[11], (const float*)d_in[13],
                          (const float*)d_in[15], (const float*)d_in[17]};
    const float* bk[4] = {(const float*)d_in[12], (const float*)d_in[14],
                          (const float*)d_in[16], (const float*)d_in[18]};

    float* ws  = (float*)d_ws;
    float* FQ  = ws;
    float* FK  = ws + 2097152;
    float* CN  = ws + 4194304;
    float* SN  = ws + 4456448;
    float* CM  = ws + 4718592;
    float* SM  = ws + 5767168;
    float* TcQ = ws + 6815744;
    float* TsQ = TcQ + 2097152;
    float* TcK = TsQ + 2097152;
    float* TsK = TcK + 2097152;
    float* Qp  = ws + 6815744;          // overwrites T region (dead after stage2)
    float* Kp  = Qp + 8388608;

    float* ctx      = (float*)d_out;
    float* attn_out = ctx + 2097152;

    hipMemsetAsync(attn_out, 0, 131072 * sizeof(float), stream);

    gen_mats<<<5120, 256, 0, stream>>>(CN, SN, CM, SM);

    // stage 1: T = X * C_N / X * S_N   (X = input viewed as (4096, 512))
    gemm_nn<<<dim3(8, 64), 256, 0, stream>>>(Q, CN, TcQ, 4096, 512, 512);
    gemm_nn<<<dim3(8, 64), 256, 0, stream>>>(Q, SN, TsQ, 4096, 512, 512);
    gemm_nn<<<dim3(8, 64), 256, 0, stream>>>(K, CN, TcK, 4096, 512, 512);
    gemm_nn<<<dim3(8, 64), 256, 0, stream>>>(K, SN, TsK, 4096, 512, 512);

    // stage 2: F = C_M*Tc - S_M*Ts  (batched over input x batch)
    dft_stage2<<<dim3(8, 16, 8), 256, 0, stream>>>(CM, SM, TcQ, TsQ, TcK, TsK, FQ, FK);

    // multi-scale conv gathers (writes Qp/Kp over the dead T region)
    gen_conv<1><<<8192, 256, 0, stream>>>(FQ, Qp, wq[0], bq[0], 0);
    gen_conv<3><<<8192, 256, 0, stream>>>(FQ, Qp, wq[1], bq[1], 1);
    gen_conv<6><<<8192, 256, 0, stream>>>(FQ, Qp, wq[2], bq[2], 2);
    gen_conv<9><<<8192, 256, 0, stream>>>(FQ, Qp, wq[3], bq[3], 3);
    gen_conv<1><<<8192, 256, 0, stream>>>(FK, Kp, wk[0], bk[0], 0);
    gen_conv<3><<<8192, 256, 0, stream>>>(FK, Kp, wk[1], bk[1], 1);
    gen_conv<6><<<8192, 256, 0, stream>>>(FK, Kp, wk[2], bk[2], 2);
    gen_conv<9><<<8192, 256, 0, stream>>>(FK, Kp, wk[3], bk[3], 3);

    // fused scores + softmax(p) + sum_q  -> attn_out
    scores_attn<<<dim3(16, 16, 32), 256, 0, stream>>>(Qp, Kp, attn_out);

    // context = colsum(V) broadcast over q
    context_kernel<<<32, 256, 0, stream>>>(V, ctx);
}

// Round 2
// 1150.191 us; speedup vs baseline: 1.1333x; 1.1333x over previous
//
#include <hip/hip_runtime.h>

// Problem constants: Q,K,V (4,8,1024,64) f32.
#define BATCH 4
#define HEADS 8
#define SEQ   1024
#define DIM   64
#define NCOL  512            // HEADS*DIM, columns of the flat (1024,512) view
#define SCALE 0.125f

// ws layout (float offsets)
//  FQ:   0          (4*1024*512 = 2097152)
//  FK:   2097152
//  CN:   4194304    (512*512   = 262144)
//  SN:   4456448
//  CM:   4718592    (1024*1024 = 1048576)
//  SM:   5767168
//  T:    6815744    (4 arrays * 2097152 = 8388608)   [dead after stage2]
//  Qp:   6815744    (8388608)  -- overwrites T region
//  Kp:   15204352   (8388608)
//  end:  23592960 floats = 94,371,840 bytes
#define WS_FLOATS_NEEDED 23592960ull

// ---------------------------------------------------------------- trig tables
__global__ void gen_mats(float* __restrict__ CN, float* __restrict__ SN,
                         float* __restrict__ CM, float* __restrict__ SM) {
    int idx = blockIdx.x * 256 + threadIdx.x;
    const float twopi = 6.28318530717958647692f;
    if (idx < 512 * 512) {
        int a = idx >> 9, b = idx & 511;
        int t = (a * b) & 511;
        float s, c;
        sincosf(twopi * (float)t * (1.0f / 512.0f), &s, &c);
        CN[idx] = c; SN[idx] = s;
    }
    int idx2 = idx - 512 * 512;
    if (idx2 >= 0 && idx2 < 1024 * 1024) {
        int a = idx2 >> 10, b = idx2 & 1023;
        int t = (a * b) & 1023;
        float s, c;
        sincosf(twopi * (float)t * (1.0f / 1024.0f), &s, &c);
        CM[idx2] = c; SM[idx2] = s;
    }
}

// ---------------- stage1 (fused cos+sin):  Tc = X*CN, Ts = X*SN, cols 0..319
// X viewed (4096, 512) row-major. A-tile transposed in LDS for b128 reads.
__global__ __launch_bounds__(256) void stage1_fused(
        const float* __restrict__ Qg, const float* __restrict__ Kg,
        const float* __restrict__ CN, const float* __restrict__ SN,
        float* __restrict__ TcQ, float* __restrict__ TsQ,
        float* __restrict__ TcK, float* __restrict__ TsK) {
    const float* X = blockIdx.z ? Kg : Qg;
    float* Tc = blockIdx.z ? TcK : TcQ;
    float* Ts = blockIdx.z ? TsK : TsQ;
    __shared__ float At[16][68];                  // [kk][m]
    __shared__ float Bc[16][68], Bs[16][68];      // [kk][n]
    int m0 = blockIdx.y * 64, n0 = blockIdx.x * 64;
    int tn = threadIdx.x & 15, tm = threadIdx.x >> 4;
    int colA = threadIdx.x & 15, rowA = threadIdx.x >> 4;
    int colB = threadIdx.x & 63, rowB = threadIdx.x >> 6;
    float accC[4][4] = {}, accS[4][4] = {};
    for (int k0 = 0; k0 < 512; k0 += 16) {
#pragma unroll
        for (int r = 0; r < 4; r++)
            At[colA][rowA + 16 * r] = X[(size_t)(m0 + rowA + 16 * r) * 512 + k0 + colA];
#pragma unroll
        for (int r = 0; r < 4; r++) {
            Bc[rowB + 4 * r][colB] = CN[(size_t)(k0 + rowB + 4 * r) * 512 + n0 + colB];
            Bs[rowB + 4 * r][colB] = SN[(size_t)(k0 + rowB + 4 * r) * 512 + n0 + colB];
        }
        __syncthreads();
#pragma unroll
        for (int kk = 0; kk < 16; kk++) {
            float4 a  = *(const float4*)&At[kk][tm * 4];
            float4 bc = *(const float4*)&Bc[kk][tn * 4];
            float4 bs = *(const float4*)&Bs[kk][tn * 4];
            float av[4]  = {a.x, a.y, a.z, a.w};
            float bcv[4] = {bc.x, bc.y, bc.z, bc.w};
            float bsv[4] = {bs.x, bs.y, bs.z, bs.w};
#pragma unroll
            for (int i = 0; i < 4; i++)
#pragma unroll
                for (int j = 0; j < 4; j++) {
                    accC[i][j] += av[i] * bcv[j];
                    accS[i][j] += av[i] * bsv[j];
                }
        }
        __syncthreads();
    }
#pragma unroll
    for (int i = 0; i < 4; i++) {
        size_t rbase = (size_t)(m0 + tm * 4 + i) * 512 + n0 + tn * 4;
        *(float4*)&Tc[rbase] = make_float4(accC[i][0], accC[i][1], accC[i][2], accC[i][3]);
        *(float4*)&Ts[rbase] = make_float4(accS[i][0], accS[i][1], accS[i][2], accS[i][3]);
    }
}

// ---------------- stage2 (fused):  F = CM*Tc - SM*Ts, cols 0..319, z = 8
__global__ __launch_bounds__(256) void stage2_fused(
        const float* __restrict__ CM, const float* __restrict__ SM,
        const float* __restrict__ TcQ, const float* __restrict__ TsQ,
        const float* __restrict__ TcK, const float* __restrict__ TsK,
        float* __restrict__ FQ, float* __restrict__ FK) {
    int z = blockIdx.z, inp = z >> 2, b = z & 3;
    const float* Tc = (inp ? TcK : TcQ) + (size_t)b * 524288;
    const float* Ts = (inp ? TsK : TsQ) + (size_t)b * 524288;
    float* F = (inp ? FK : FQ) + (size_t)b * 524288;
    __shared__ float Ac[16][68], Asn[16][68];     // [kk][m]
    __shared__ float Bc[16][68], Bs[16][68];      // [kk][n]
    int m0 = blockIdx.y * 64, n0 = blockIdx.x * 64;
    int tn = threadIdx.x & 15, tm = threadIdx.x >> 4;
    int colA = threadIdx.x & 15, rowA = threadIdx.x >> 4;
    int colB = threadIdx.x & 63, rowB = threadIdx.x >> 6;
    float acc[4][4] = {};
    for (int k0 = 0; k0 < 1024; k0 += 16) {
#pragma unroll
        for (int r = 0; r < 4; r++) {
            Ac [colA][rowA + 16 * r] = CM[(size_t)(m0 + rowA + 16 * r) * 1024 + k0 + colA];
            Asn[colA][rowA + 16 * r] = SM[(size_t)(m0 + rowA + 16 * r) * 1024 + k0 + colA];
        }
#pragma unroll
        for (int r = 0; r < 4; r++) {
            Bc[rowB + 4 * r][colB] = Tc[(size_t)(k0 + rowB + 4 * r) * 512 + n0 + colB];
            Bs[rowB + 4 * r][colB] = Ts[(size_t)(k0 + rowB + 4 * r) * 512 + n0 + colB];
        }
        __syncthreads();
#pragma unroll
        for (int kk = 0; kk < 16; kk++) {
            float4 ac = *(const float4*)&Ac[kk][tm * 4];
            float4 as = *(const float4*)&Asn[kk][tm * 4];
            float4 bc = *(const float4*)&Bc[kk][tn * 4];
            float4 bs = *(const float4*)&Bs[kk][tn * 4];
            float acv[4] = {ac.x, ac.y, ac.z, ac.w};
            float asv[4] = {as.x, as.y, as.z, as.w};
            float bcv[4] = {bc.x, bc.y, bc.z, bc.w};
            float bsv[4] = {bs.x, bs.y, bs.z, bs.w};
#pragma unroll
            for (int i = 0; i < 4; i++)
#pragma unroll
                for (int j = 0; j < 4; j++)
                    acc[i][j] += acv[i] * bcv[j] - asv[i] * bsv[j];
        }
        __syncthreads();
    }
#pragma unroll
    for (int i = 0; i < 4; i++) {
        size_t rbase = (size_t)(m0 + tm * 4 + i) * 512 + n0 + tn * 4;
        *(float4*)&F[rbase] = make_float4(acc[i][0], acc[i][1], acc[i][2], acc[i][3]);
    }
}

// ------------- mirror: F[m, n] = F[(1024-m)%1024, 512-n]  for n in 257..511
__global__ void mirror_f(float* __restrict__ FQ, float* __restrict__ FK) {
    int z = blockIdx.x >> 10;
    int m = blockIdx.x & 1023;
    float* F = (z >= 4) ? (FK + (size_t)(z - 4) * 524288) : (FQ + (size_t)z * 524288);
    int t = threadIdx.x;
    if (t < 255) {
        int n = 257 + t;
        F[(size_t)m * 512 + n] = F[(size_t)((1024 - m) & 1023) * 512 + (512 - n)];
    }
}

// ------------------------------------ multi-scale conv gather (all 4 scales)
template <int C>
__device__ inline float conv_gather(const float* __restrict__ Fb, int rb, int cb, int d,
                                    const float* __restrict__ w) {
    float acc = 0.f;
#pragma unroll
    for (int ci = 0; ci < C; ci++) {
        int u = ci * 64 + d;
        int q = u / C, r = u - q * C;
        int row = rb + r - C;
        int col = cb + q - C;
        if (row >= 0 && col >= 0)
            acc += w[ci] * Fb[(row << 9) + col];
    }
    return acc;
}

__global__ __launch_bounds__(256) void conv_all(const float* __restrict__ F,
        float* __restrict__ out,
        const float* __restrict__ w1, const float* __restrict__ bb1,
        const float* __restrict__ w3, const float* __restrict__ bb3,
        const float* __restrict__ w6, const float* __restrict__ bb6,
        const float* __restrict__ w9, const float* __restrict__ bb9) {
    int idx = blockIdx.x * 256 + threadIdx.x;
    int d = idx & 63;
    int l = (idx >> 6) & 1023;
    int h = (idx >> 16) & 7;
    int b = idx >> 19;
    int g = (h << 10) + l;
    int rb = g >> 3;
    int cb = (g & 7) << 6;
    const float* Fb = F + (size_t)b * (SEQ * NCOL);
    size_t ob = (size_t)((b * 8 + h) * 4) * 65536 + l * 64 + d;
    out[ob]             = conv_gather<1>(Fb, rb, cb, d, w1) + bb1[0];
    out[ob + 65536]     = conv_gather<3>(Fb, rb, cb, d, w3) + bb3[0];
    out[ob + 2 * 65536] = conv_gather<6>(Fb, rb, cb, d, w6) + bb6[0];
    out[ob + 3 * 65536] = conv_gather<9>(Fb, rb, cb, d, w9) + bb9[0];
}

// ------------- fused scores (4 GEMMs K=64) + softmax over p + q-reduction
__global__ __launch_bounds__(256) void scores_attn(const float* __restrict__ Qp,
                                                   const float* __restrict__ Kp,
                                                   float* __restrict__ attn_out) {
    int bh = blockIdx.z;
    int k0 = blockIdx.x * 64, q0 = blockIdx.y * 64;
    __shared__ float As[64][68];
    __shared__ float Bs[64][68];
    int tx = threadIdx.x & 15, ty = threadIdx.x >> 4;
    float acc[4][4][4];   // [p][i(q)][j(k)]
#pragma unroll
    for (int p = 0; p < 4; p++)
#pragma unroll
        for (int i = 0; i < 4; i++)
#pragma unroll
            for (int j = 0; j < 4; j++) acc[p][i][j] = 0.f;

    for (int p = 0; p < 4; p++) {
        const float* Ab = Qp + (size_t)(bh * 4 + p) * 65536 + (size_t)q0 * 64;
        const float* Bb = Kp + (size_t)(bh * 4 + p) * 65536 + (size_t)k0 * 64;
        __syncthreads();
        {
            int c4 = (threadIdx.x & 15) * 4, row = threadIdx.x >> 4;
#pragma unroll
            for (int r = 0; r < 4; r++) {
                float4 va = *(const float4*)(Ab + (size_t)(row + 16 * r) * 64 + c4);
                As[row + 16 * r][c4 + 0] = va.x; As[row + 16 * r][c4 + 1] = va.y;
                As[row + 16 * r][c4 + 2] = va.z; As[row + 16 * r][c4 + 3] = va.w;
                float4 vb = *(const float4*)(Bb + (size_t)(row + 16 * r) * 64 + c4);
                Bs[row + 16 * r][c4 + 0] = vb.x; Bs[row + 16 * r][c4 + 1] = vb.y;
                Bs[row + 16 * r][c4 + 2] = vb.z; Bs[row + 16 * r][c4 + 3] = vb.w;
            }
        }
        __syncthreads();
#pragma unroll 16
        for (int kk = 0; kk < 64; kk++) {
            float a[4], bv[4];
#pragma unroll
            for (int i = 0; i < 4; i++) a[i] = As[ty + 16 * i][kk];
#pragma unroll
            for (int j = 0; j < 4; j++) bv[j] = Bs[tx + 16 * j][kk];
#pragma unroll
            for (int i = 0; i < 4; i++)
#pragma unroll
                for (int j = 0; j < 4; j++) acc[p][i][j] += a[i] * bv[j];
        }
    }
    __syncthreads();

    float qsum[4][4];     // [p][j]
#pragma unroll
    for (int p = 0; p < 4; p++)
#pragma unroll
        for (int j = 0; j < 4; j++) qsum[p][j] = 0.f;
#pragma unroll
    for (int i = 0; i < 4; i++)
#pragma unroll
        for (int j = 0; j < 4; j++) {
            float s0 = acc[0][i][j] * SCALE, s1 = acc[1][i][j] * SCALE;
            float s2 = acc[2][i][j] * SCALE, s3 = acc[3][i][j] * SCALE;
            float m = fmaxf(fmaxf(s0, s1), fmaxf(s2, s3));
            float e0 = expf(s0 - m), e1 = expf(s1 - m);
            float e2 = expf(s2 - m), e3 = expf(s3 - m);
            float inv = 1.0f / (e0 + e1 + e2 + e3);
            qsum[0][j] += e0 * inv; qsum[1][j] += e1 * inv;
            qsum[2][j] += e2 * inv; qsum[3][j] += e3 * inv;
        }

    float* red = &As[0][0];   // 4*64*16 = 4096 floats, fits in As
#pragma unroll
    for (int p = 0; p < 4; p++)
#pragma unroll
        for (int j = 0; j < 4; j++)
            red[(p * 64 + tx + 16 * j) * 16 + ty] = qsum[p][j];
    __syncthreads();
    int p = threadIdx.x >> 6, k = threadIdx.x & 63;
    float s = 0.f;
#pragma unroll
    for (int t = 0; t < 16; t++) s += red[(p * 64 + k) * 16 + t];
    atomicAdd(&attn_out[(size_t)(bh * 4 + p) * 1024 + k0 + k], s);
}

// ------------------------------- context[b,h,q,:] = colsum(V[b,h]) broadcast
__global__ __launch_bounds__(256) void context_kernel(const float* __restrict__ V,
                                                      float* __restrict__ out) {
    int bh = blockIdx.x;
    const float* Vb = V + (size_t)bh * 65536;
    __shared__ float part[4][64];
    __shared__ float colsum[64];
    int d = threadIdx.x & 63, grp = threadIdx.x >> 6;
    float s = 0.f;
    for (int r = grp; r < 1024; r += 4) s += Vb[r * 64 + d];
    part[grp][d] = s;
    __syncthreads();
    if (threadIdx.x < 64) colsum[d] = part[0][d] + part[1][d] + part[2][d] + part[3][d];
    __syncthreads();
    float val = colsum[d];
    float* ob = out + (size_t)bh * 65536;
    for (int q = grp; q < 1024; q += 4) ob[q * 64 + d] = val;
}

// ---------------------------------------------------------------------------
extern "C" void kernel_launch(void* const* d_in, const int* in_sizes, int n_in,
                              void* d_out, int out_size, void* d_ws, size_t ws_size,
                              hipStream_t stream) {
    if (n_in < 19) return;
    if ((size_t)ws_size < WS_FLOATS_NEEDED * sizeof(float)) return;  // visible failure
    const float* Q = (const float*)d_in[0];
    const float* K = (const float*)d_in[1];
    const float* V = (const float*)d_in[2];
    const float* wq[4] = {(const float*)d_in[3], (const float*)d_in[5],
                          (const float*)d_in[7], (const float*)d_in[9]};
    const float* bq[4] = {(const float*)d_in[4], (const float*)d_in[6],
                          (const float*)d_in[8], (const float*)d_in[10]};
    const float* wk[4] = {(const float*)d_in[11], (const float*)d_in[13],
                          (const float*)d_in[15], (const float*)d_in[17]};
    const float* bk[4] = {(const float*)d_in[12], (const float*)d_in[14],
                          (const float*)d_in[16], (const float*)d_in[18]};

    float* ws  = (float*)d_ws;
    float* FQ  = ws;
    float* FK  = ws + 2097152;
    float* CN  = ws + 4194304;
    float* SN  = ws + 4456448;
    float* CM  = ws + 4718592;
    float* SM  = ws + 5767168;
    float* TcQ = ws + 6815744;
    float* TsQ = TcQ + 2097152;
    float* TcK = TsQ + 2097152;
    float* TsK = TcK + 2097152;
    float* Qp  = ws + 6815744;          // overwrites T region (dead after stage2)
    float* Kp  = Qp + 8388608;

    float* ctx      = (float*)d_out;
    float* attn_out = ctx + 2097152;

    hipMemsetAsync(attn_out, 0, 131072 * sizeof(float), stream);

    gen_mats<<<5120, 256, 0, stream>>>(CN, SN, CM, SM);

    // stage 1 fused: Tc/Ts = X * CN/SN, columns 0..319 only (Hermitian symmetry)
    stage1_fused<<<dim3(5, 64, 2), 256, 0, stream>>>(Q, K, CN, SN, TcQ, TsQ, TcK, TsK);

    // stage 2 fused: F = CM*Tc - SM*Ts, columns 0..319, all 8 (input,batch)
    stage2_fused<<<dim3(5, 16, 8), 256, 0, stream>>>(CM, SM, TcQ, TsQ, TcK, TsK, FQ, FK);

    // fill F columns 257..511 by conjugate symmetry
    mirror_f<<<8192, 256, 0, stream>>>(FQ, FK);

    // multi-scale conv gathers, all 4 scales fused per input
    conv_all<<<8192, 256, 0, stream>>>(FQ, Qp, wq[0], bq[0], wq[1], bq[1],
                                       wq[2], bq[2], wq[3], bq[3]);
    conv_all<<<8192, 256, 0, stream>>>(FK, Kp, wk[0], bk[0], wk[1], bk[1],
                                       wk[2], bk[2], wk[3], bk[3]);

    // fused scores + softmax(p) + sum_q  -> attn_out
    scores_attn<<<dim3(16, 16, 32), 256, 0, stream>>>(Qp, Kp, attn_out);

    // context = colsum(V) broadcast over q
    context_kernel<<<32, 256, 0, stream>>>(V, ctx);
}